// Round 3
// baseline (1171.997 us; speedup 1.0000x reference)
//
#include <hip/hip_runtime.h>
#include <math.h>

typedef unsigned short ushort_t;
typedef short short8 __attribute__((ext_vector_type(8)));
typedef float f32x4  __attribute__((ext_vector_type(4)));

#define N_ROWS 8192
#define D_DIM  2048
#define K_CODES 10000
#define EPSF   1e-12f

#define BMT 256
#define BKT 64
#define NT_K 96          // 3 * D_DIM / BKT  (K-concat: Ah*Bh | Al*Bh | Ah*Bl)
#define MTILES 32        // 8192/256
#define NTILES 40        // ceil(10000/256)

__device__ __forceinline__ unsigned short f2bf(float f) {
  unsigned u = __float_as_uint(f);
  unsigned r = (u + 0x7fffu + ((u >> 16) & 1u)) >> 16;   // RNE
  return (unsigned short)r;
}
__device__ __forceinline__ float bf2f(unsigned short h) {
  return __uint_as_float(((unsigned)h) << 16);
}

__device__ __forceinline__ void stage16(const ushort_t* g, ushort_t* l) {
  __builtin_amdgcn_global_load_lds(
      (const __attribute__((address_space(1))) unsigned int*)g,
      (__attribute__((address_space(3))) unsigned int*)l, 16, 0, 0);
}

__device__ __forceinline__ float block_reduce_sum(float v) {
  #pragma unroll
  for (int o = 32; o > 0; o >>= 1) v += __shfl_down(v, o, 64);
  __shared__ float ls[4];
  int lane = threadIdx.x & 63;
  int wid  = threadIdx.x >> 6;
  if (lane == 0) ls[wid] = v;
  __syncthreads();
  v = (threadIdx.x < 4) ? ls[threadIdx.x] : 0.0f;
  if (wid == 0) {
    v += __shfl_down(v, 2, 64);
    v += __shfl_down(v, 1, 64);
  }
  __syncthreads();
  return v;   // valid in thread 0
}

// One block per row: normalize, split into bf16 hi/lo, store sq = sum(xn^2)
__global__ __launch_bounds__(256) void norm_split_kernel(
    const float* __restrict__ src,
    ushort_t* __restrict__ hi, ushort_t* __restrict__ lo,
    float* __restrict__ sq_out)
{
  int row = blockIdx.x;
  int tid = threadIdx.x;
  const float* rp = src + (size_t)row * D_DIM;
  float4 v0 = *(const float4*)(rp + tid * 8);
  float4 v1 = *(const float4*)(rp + tid * 8 + 4);
  float s = v0.x*v0.x + v0.y*v0.y + v0.z*v0.z + v0.w*v0.w
          + v1.x*v1.x + v1.y*v1.y + v1.z*v1.z + v1.w*v1.w;
  s = block_reduce_sum(s);
  __shared__ float sh_inv;
  if (tid == 0) sh_inv = 1.0f / fmaxf(sqrtf(s), EPSF);
  __syncthreads();
  float inv = sh_inv;

  float xs[8] = {v0.x, v0.y, v0.z, v0.w, v1.x, v1.y, v1.z, v1.w};
  unsigned short hb[8], lb[8];
  float t = 0.0f;
  #pragma unroll
  for (int i = 0; i < 8; ++i) {
    float xn = xs[i] * inv;
    t += xn * xn;
    unsigned short h = f2bf(xn);
    hb[i] = h;
    lb[i] = f2bf(xn - bf2f(h));
  }
  *(short8*)(hi + (size_t)row * D_DIM + tid * 8) = *(short8*)hb;
  *(short8*)(lo + (size_t)row * D_DIM + tid * 8) = *(short8*)lb;
  t = block_reduce_sum(t);
  if (tid == 0) sq_out[row] = t;
}

// ------------- 256x256 8-phase MFMA dist+argmin kernel -------------
// grid = 1280 flat (32 mtiles x 40 ntiles), block = 512 (8 waves, 2Mx4N)
// K-concat GEMM: seg0 Ah*Bh, seg1 Al*Bh, seg2 Ah*Bl  (K = 96 steps of 64)
// LDS: A[2][256][64], B[2][256][64] bf16, XOR-swizzled (slot ^= row&7).

#define READ_A(mh) { \
  _Pragma("unroll") for (int mi = 0; mi < 4; ++mi) \
  _Pragma("unroll") for (int kc = 0; kc < 2; ++kc) { \
    int r = (mh)*128 + wr*64 + mi*16 + t16; \
    int sl = (kc*4 + h4) ^ (r & 7); \
    af[mi][kc] = *(const short8*)&lA[buf][r*64 + sl*8]; } }

#define READ_B(nh, DST) { \
  _Pragma("unroll") for (int ni = 0; ni < 2; ++ni) \
  _Pragma("unroll") for (int kc = 0; kc < 2; ++kc) { \
    int r = (nh)*128 + wc*32 + ni*16 + t16; \
    int sl = (kc*4 + h4) ^ (r & 7); \
    DST[ni][kc] = *(const short8*)&lB[buf][r*64 + sl*8]; } }

#define MFMA_Q(mh, nh, BF) { \
  _Pragma("unroll") for (int mi = 0; mi < 4; ++mi) \
  _Pragma("unroll") for (int ni = 0; ni < 2; ++ni) \
  _Pragma("unroll") for (int kc = 0; kc < 2; ++kc) \
    acc[(mh)*4+mi][(nh)*2+ni] = __builtin_amdgcn_mfma_f32_16x16x32_bf16( \
        af[mi][kc], BF[ni][kc], acc[(mh)*4+mi][(nh)*2+ni], 0, 0, 0); }

#define STAGE_A(BF, HH, ASRC, KKO) { \
  stage16((ASRC) + (size_t)(row0 + (HH)*128 + prow0) * D_DIM + (KKO) + lsl, \
          lA[BF] + (HH)*8192 + c0*512); \
  stage16((ASRC) + (size_t)(row0 + (HH)*128 + prow1) * D_DIM + (KKO) + lsl, \
          lA[BF] + (HH)*8192 + c0*512 + 512); }

#define STAGE_B(BF, HH, BSRC, KKO) { \
  int r0_ = col0 + (HH)*128 + prow0; r0_ = r0_ < K_CODES ? r0_ : K_CODES - 1; \
  int r1_ = col0 + (HH)*128 + prow1; r1_ = r1_ < K_CODES ? r1_ : K_CODES - 1; \
  stage16((BSRC) + (size_t)r0_ * D_DIM + (KKO) + lsl, \
          lB[BF] + (HH)*8192 + c0*512); \
  stage16((BSRC) + (size_t)r1_ * D_DIM + (KKO) + lsl, \
          lB[BF] + (HH)*8192 + c0*512 + 512); }

__global__ __launch_bounds__(512, 1) void dist_argmin_kernel(
    const ushort_t* __restrict__ Ah, const ushort_t* __restrict__ Al,
    const ushort_t* __restrict__ Bh, const ushort_t* __restrict__ Bl,
    const float* __restrict__ wsq,
    float* __restrict__ pdist, int* __restrict__ pidx)
{
  __shared__ ushort_t lA[2][16384];
  __shared__ ushort_t lB[2][16384];

  const int tid  = threadIdx.x;
  const int lane = tid & 63;
  const int w8   = tid >> 6;        // wave 0..7
  const int wr   = w8 >> 2;         // wave row 0..1
  const int wc   = w8 & 3;          // wave col 0..3
  const int t16  = lane & 15;
  const int h4   = lane >> 4;       // 0..3

  // bijective XCD swizzle (1280 % 8 == 0): each XCD gets 5 contiguous ntiles
  int bid = blockIdx.x;
  int swz = (bid & 7) * 160 + (bid >> 3);
  const int mtile = swz & 31;
  const int ntile = swz >> 5;
  const int row0 = mtile * BMT;
  const int col0 = ntile * BMT;

  // staging geometry: chunk c = w8*2 + j covers 8 rows of a 128-row half-tile
  const int sub  = lane >> 3;                    // 0..7
  const int lsl  = ((lane & 7) ^ sub) * 8;       // pre-swizzled source slot
  const int c0   = w8 * 2;
  const int prow0 = c0 * 8 + sub;
  const int prow1 = prow0 + 8;

  f32x4 acc[8][4];
  #pragma unroll
  for (int m = 0; m < 8; ++m)
    #pragma unroll
    for (int n = 0; n < 4; ++n) acc[m][n] = (f32x4){0.f, 0.f, 0.f, 0.f};

  // ---- prologue: stage tile 0 (order: A-h0, B-h0, B-h1, A-h1) ----
  STAGE_A(0, 0, Ah, 0);
  STAGE_B(0, 0, Bh, 0);
  STAGE_B(0, 1, Bh, 0);
  STAGE_A(0, 1, Ah, 0);
  asm volatile("s_waitcnt vmcnt(2)" ::: "memory");
  __builtin_amdgcn_s_barrier();

  short8 af[4][2], bfr0[2][2], bfr1[2][2];

  for (int kt = 0; kt < NT_K; ++kt) {
    const int buf  = kt & 1;
    const int nbuf = buf ^ 1;
    const bool hn  = (kt + 1 < NT_K);
    const int kn   = kt + 1;
    const ushort_t* As = ((kn >> 5) == 1) ? Al : Ah;
    const ushort_t* Bs = ((kn >> 5) == 2) ? Bl : Bh;
    const int kk = (kn & 31) * BKT;

    // ---- phase 1: quadrant (m0, n0) ----
    READ_A(0);
    READ_B(0, bfr0);
    if (hn) STAGE_A(nbuf, 0, As, kk);
    __builtin_amdgcn_s_barrier();
    asm volatile("s_waitcnt lgkmcnt(0)" ::: "memory");
    __builtin_amdgcn_sched_barrier(0);
    __builtin_amdgcn_s_setprio(1);
    MFMA_Q(0, 0, bfr0);
    __builtin_amdgcn_s_setprio(0);
    __builtin_amdgcn_s_barrier();

    // ---- phase 2: quadrant (m0, n1) ----
    READ_B(1, bfr1);
    if (hn) {
      STAGE_B(nbuf, 0, Bs, kk);
      asm volatile("s_waitcnt vmcnt(4)" ::: "memory");  // retire prev-tile A-h1
    } else {
      asm volatile("s_waitcnt vmcnt(0)" ::: "memory");  // peeled last tile
    }
    __builtin_amdgcn_s_barrier();
    asm volatile("s_waitcnt lgkmcnt(0)" ::: "memory");
    __builtin_amdgcn_sched_barrier(0);
    __builtin_amdgcn_s_setprio(1);
    MFMA_Q(0, 1, bfr1);
    __builtin_amdgcn_s_setprio(0);
    __builtin_amdgcn_s_barrier();

    // ---- phase 3: quadrant (m1, n1) ----
    READ_A(1);
    if (hn) STAGE_B(nbuf, 1, Bs, kk);
    __builtin_amdgcn_s_barrier();
    asm volatile("s_waitcnt lgkmcnt(0)" ::: "memory");
    __builtin_amdgcn_sched_barrier(0);
    __builtin_amdgcn_s_setprio(1);
    MFMA_Q(1, 1, bfr1);
    __builtin_amdgcn_s_setprio(0);
    __builtin_amdgcn_s_barrier();

    // ---- phase 4: quadrant (m1, n0) ----
    READ_B(0, bfr0);
    if (hn) {
      STAGE_A(nbuf, 1, As, kk);
      asm volatile("s_waitcnt vmcnt(2)" ::: "memory");  // retire this tile's ph1-3 loads
    }
    __builtin_amdgcn_s_barrier();
    asm volatile("s_waitcnt lgkmcnt(0)" ::: "memory");
    __builtin_amdgcn_sched_barrier(0);
    __builtin_amdgcn_s_setprio(1);
    MFMA_Q(1, 0, bfr0);
    __builtin_amdgcn_s_setprio(0);
    __builtin_amdgcn_s_barrier();
  }

  // ---- epilogue: dist = wsq[c] - 2*dot, fused argmin ----
  float* redd = (float*)&lA[0][0];   // [256][4]
  int*   redi = (int*)  &lA[1][0];   // [256][4]

  float wsqr[4]; int colr[4];
  #pragma unroll
  for (int n = 0; n < 4; ++n) {
    int col = col0 + ((n & 2) ? 128 : 0) + wc * 32 + ((n & 1) ? 16 : 0) + t16;
    colr[n] = col;
    wsqr[n] = (col < K_CODES) ? wsq[col] : __int_as_float(0x7f800000);
  }
  #pragma unroll
  for (int m = 0; m < 8; ++m) {
    int rloc = ((m & 4) ? 128 : 0) + wr * 64 + (m & 3) * 16 + h4 * 4;
    #pragma unroll
    for (int j = 0; j < 4; ++j) {
      float bd = INFINITY; int bi = 0x7fffffff;
      #pragma unroll
      for (int n = 0; n < 4; ++n) {            // ascending col order
        float d = wsqr[n] - 2.0f * acc[m][n][j];
        if (d < bd) { bd = d; bi = colr[n]; }
      }
      #pragma unroll
      for (int off = 1; off < 16; off <<= 1) {
        float od = __shfl_xor(bd, off, 64);
        int   oi = __shfl_xor(bi, off, 64);
        if (od < bd || (od == bd && oi < bi)) { bd = od; bi = oi; }
      }
      if (t16 == 0) { redd[(rloc + j) * 4 + wc] = bd; redi[(rloc + j) * 4 + wc] = bi; }
    }
  }
  __syncthreads();
  if (tid < 256) {
    float bd = redd[tid * 4]; int bi = redi[tid * 4];
    #pragma unroll
    for (int q = 1; q < 4; ++q) {
      float d = redd[tid * 4 + q]; int ix = redi[tid * 4 + q];
      if (d < bd || (d == bd && ix < bi)) { bd = d; bi = ix; }
    }
    pdist[(size_t)ntile * N_ROWS + row0 + tid] = bd;
    pidx [(size_t)ntile * N_ROWS + row0 + tid] = bi;
  }
}

__global__ __launch_bounds__(256) void argmin_reduce_kernel(
    const float* __restrict__ pdist, const int* __restrict__ pidx,
    int* __restrict__ idx_out, float* __restrict__ idxf_out)
{
  int row = blockIdx.x * 256 + threadIdx.x;
  if (row >= N_ROWS) return;
  float b = INFINITY; int bi = 0x7fffffff;
  for (int s = 0; s < NTILES; ++s) {
    float d = pdist[(size_t)s * N_ROWS + row];
    int  ix = pidx [(size_t)s * N_ROWS + row];
    if (d < b || (d == b && ix < bi)) { b = d; bi = ix; }
  }
  idx_out[row]  = bi;
  idxf_out[row] = (float)bi;
}

__global__ __launch_bounds__(256) void gather_kernel(
    const float* __restrict__ x, const float* __restrict__ w,
    const int* __restrict__ idx, float* __restrict__ out,
    float* __restrict__ lpart)
{
  int row = blockIdx.x;
  int tid = threadIdx.x;
  int id = idx[row];
  const float4* wr_ = (const float4*)(w + (size_t)id * D_DIM);
  const float4* xr  = (const float4*)(x + (size_t)row * D_DIM);
  float4* outr = (float4*)(out + (size_t)row * D_DIM);
  float s = 0.0f;
  #pragma unroll
  for (int t = 0; t < 2; ++t) {
    int e = tid + t * 256;
    float4 wv = wr_[e], xv = xr[e];
    outr[e] = wv;
    float d0 = wv.x - xv.x, d1 = wv.y - xv.y, d2 = wv.z - xv.z, d3 = wv.w - xv.w;
    s += d0 * d0 + d1 * d1 + d2 * d2 + d3 * d3;
  }
  s = block_reduce_sum(s);
  if (tid == 0) lpart[row] = s;
}

__global__ __launch_bounds__(256) void loss_kernel(const float* __restrict__ lpart,
                                                   float* __restrict__ loss_out)
{
  int tid = threadIdx.x;
  double s = 0.0;
  for (int t = tid; t < N_ROWS; t += 256) s += (double)lpart[t];
  __shared__ double sd[256];
  sd[tid] = s;
  __syncthreads();
  #pragma unroll
  for (int o = 128; o > 0; o >>= 1) {
    if (tid < o) sd[tid] += sd[tid + o];
    __syncthreads();
  }
  if (tid == 0)
    loss_out[0] = (float)(1.25 * sd[0] / (double)((size_t)N_ROWS * (size_t)D_DIM));
}

extern "C" void kernel_launch(void* const* d_in, const int* in_sizes, int n_in,
                              void* d_out, int out_size, void* d_ws, size_t ws_size,
                              hipStream_t stream) {
  const float* x = (const float*)d_in[0];
  const float* w = (const float*)d_in[1];
  float* out = (float*)d_out;
  char*  ws  = (char*)d_ws;

  size_t off = 0;
  auto alloc = [&](size_t bytes) {
    size_t o = off;
    off = (off + bytes + 255) & ~(size_t)255;
    return o;
  };
  const size_t szA1 = (size_t)N_ROWS * D_DIM * 2;   // one x-split matrix
  const size_t szB1 = (size_t)K_CODES * D_DIM * 2;  // one w-split matrix

  ushort_t* Bh = (ushort_t*)(ws + alloc(szB1));
  ushort_t* Bl = (ushort_t*)(ws + alloc(szB1));
  float* wsq   = (float*)(ws + alloc((size_t)K_CODES * 4));
  float* xsq   = (float*)(ws + alloc((size_t)N_ROWS * 4));
  float* pdist = (float*)(ws + alloc((size_t)NTILES * N_ROWS * 4));
  int*   pidx  = (int*)  (ws + alloc((size_t)NTILES * N_ROWS * 4));
  int*   idx   = (int*)  (ws + alloc((size_t)N_ROWS * 4));
  float* lpart = (float*)(ws + alloc((size_t)N_ROWS * 4));

  ushort_t* Ahp;
  ushort_t* Alp;
  if (ws_size >= off + 2 * szA1) {
    Ahp = (ushort_t*)(ws + alloc(szA1));
    Alp = (ushort_t*)(ws + alloc(szA1));
  } else {
    // quantized region is exactly N*D*4 = 2*szA1 bytes; consumed by dist
    // kernel, then overwritten by gather_kernel (stream-ordered, safe)
    Ahp = (ushort_t*)out;
    Alp = Ahp + (size_t)N_ROWS * D_DIM;
  }

  float* loss_out = out + (size_t)N_ROWS * D_DIM;
  float* idxf_out = loss_out + 1;

  norm_split_kernel<<<N_ROWS, 256, 0, stream>>>(x, Ahp, Alp, xsq);
  norm_split_kernel<<<K_CODES, 256, 0, stream>>>(w, Bh, Bl, wsq);
  dist_argmin_kernel<<<MTILES * NTILES, 512, 0, stream>>>(
      Ahp, Alp, Bh, Bl, wsq, pdist, pidx);
  argmin_reduce_kernel<<<(N_ROWS + 255) / 256, 256, 0, stream>>>(
      pdist, pidx, idx, idxf_out);
  gather_kernel<<<N_ROWS, 256, 0, stream>>>(x, w, idx, out, lpart);
  loss_kernel<<<1, 256, 0, stream>>>(lpart, loss_out);
}